// Round 10
// baseline (427.404 us; speedup 1.0000x reference)
//
#include <hip/hip_runtime.h>

#define NUSERS 100000
#define NITEMS 50000
#define NNODES 150000   // NUSERS + NITEMS
#define EMB 64
#define NEDGES 4800000
#define OUTC 192        // 3 * EMB concatenated output columns
#define NEG_SLOPE 0.01f

#define BKT_SHIFT 10
#define NB 147          // ceil(NNODES / 1024)
#define G 1024          // blocks in hist/scatter passes
#define EPB 4688        // ceil(NEDGES / G), multiple of 4
#define NSCAN (NB * G)  // 150528
#define NSLICE 10       // col slices (col >> 14 in [0,9])
#define SLICE_SHIFT 14
#define NBINS (1024 * NSLICE)
#define NDEG 128        // degree bins for balance sort (clamped)

typedef __attribute__((ext_vector_type(8))) short bf16x8;
typedef __attribute__((ext_vector_type(4))) float f32x4;

__device__ __forceinline__ unsigned short f2bf(float f) {
    unsigned u = __float_as_uint(f);
    unsigned r = (u + 0x7fffu + ((u >> 16) & 1u)) >> 16;   // RN-even
    return (unsigned short)r;
}
__device__ __forceinline__ float bf2f(short s) {
    return __uint_as_float(((unsigned)(unsigned short)s) << 16);
}

// ---------------- ego0 build: gather embeddings -> out cols 0:64 AND bf16 egoc0
__global__ void build_ego(const int* __restrict__ ui, const int* __restrict__ ii,
                          const float* __restrict__ uemb, const float* __restrict__ iemb,
                          float* __restrict__ out, unsigned short* __restrict__ egoc) {
    int gid = blockIdx.x * blockDim.x + threadIdx.x;   // one float4 per thread
    int r = gid >> 4, p = gid & 15;
    if (r >= NNODES) return;
    const float* src = (r < NUSERS) ? (uemb + (size_t)ui[r] * EMB)
                                    : (iemb + (size_t)ii[r - NUSERS] * EMB);
    float4 v = ((const float4*)src)[p];
    *(float4*)(out + (size_t)r * OUTC + p * 4) = v;
    ushort4 o;
    o.x = f2bf(v.x); o.y = f2bf(v.y); o.z = f2bf(v.z); o.w = f2bf(v.w);
    *(ushort4*)(egoc + (size_t)r * EMB + p * 4) = o;
}

// all 4 weight matrices f32 [64][64] -> bf16 in one kernel
__global__ void conv_w4(const float* __restrict__ s0, const float* __restrict__ s1,
                        const float* __restrict__ s2, const float* __restrict__ s3,
                        unsigned short* __restrict__ d0, unsigned short* __restrict__ d1,
                        unsigned short* __restrict__ d2, unsigned short* __restrict__ d3) {
    int i = blockIdx.x * 256 + threadIdx.x;
    if (i < 4096) {
        d0[i] = f2bf(s0[i]); d1[i] = f2bf(s1[i]);
        d2[i] = f2bf(s2[i]); d3[i] = f2bf(s3[i]);
    }
}

// ---------------- CSR build: bucket partition, LDS atomics only ----------------
// P1: per-block 147-bucket LDS histogram (int4 edge reads)
__global__ __launch_bounds__(256) void bucket_hist(const int* __restrict__ rows,
                                                   int* __restrict__ hist) {
    __shared__ int h[NB];
    int tid = threadIdx.x, blk = blockIdx.x;
    if (tid < NB) h[tid] = 0;
    __syncthreads();
    int q0 = blk * (EPB / 4), q1 = q0 + (EPB / 4);
    const int qmax = NEDGES / 4;
    if (q1 > qmax) q1 = qmax;
    for (int q = q0 + tid; q < q1; q += 256) {
        int4 r4 = ((const int4*)rows)[q];
        atomicAdd(&h[r4.x >> BKT_SHIFT], 1);
        atomicAdd(&h[r4.y >> BKT_SHIFT], 1);
        atomicAdd(&h[r4.z >> BKT_SHIFT], 1);
        atomicAdd(&h[r4.w >> BKT_SHIFT], 1);
    }
    __syncthreads();
    if (tid < NB) hist[(size_t)tid * G + blk] = h[tid];   // bucket-major
}

// inclusive scan of 1024-chunks -> outp[i+1]; block totals to blksum
__global__ void scan_chunk(const int* __restrict__ counts, int* __restrict__ outp,
                           int* __restrict__ blksum, int n) {
    __shared__ int buf[1024];
    int tid = threadIdx.x;
    int gid = blockIdx.x * 1024 + tid;
    int v = (gid < n) ? counts[gid] : 0;
    buf[tid] = v;
    __syncthreads();
    for (int off = 1; off < 1024; off <<= 1) {
        int t = (tid >= off) ? buf[tid - off] : 0;
        __syncthreads();
        buf[tid] += t;
        __syncthreads();
    }
    if (gid < n) outp[gid + 1] = buf[tid];
    if (tid == 1023) blksum[blockIdx.x] = buf[tid];
}

__global__ void scan_sums(int* __restrict__ blksum, int n) {
    __shared__ int buf[256];
    int tid = threadIdx.x;
    int v = (tid < n) ? blksum[tid] : 0;
    buf[tid] = v;
    __syncthreads();
    for (int off = 1; off < 256; off <<= 1) {
        int t = (tid >= off) ? buf[tid - off] : 0;
        __syncthreads();
        buf[tid] += t;
        __syncthreads();
    }
    if (tid < n) blksum[tid] = buf[tid] - v;  // exclusive
}

__global__ void add_offsets(int* __restrict__ outp, const int* __restrict__ blksum, int n) {
    int gid = blockIdx.x * 1024 + threadIdx.x;
    if (gid < n) outp[gid + 1] += blksum[blockIdx.x];
    if (gid == 0) outp[0] = 0;
}

// P2: scatter edges into bucket-partitioned array (int4 reads, LDS cursors)
__global__ __launch_bounds__(256) void bucket_scatter(
        const int* __restrict__ rows, const int* __restrict__ cols,
        const float* __restrict__ vals, const int* __restrict__ base,
        int2* __restrict__ bedge) {
    __shared__ int cur[NB];
    int tid = threadIdx.x, blk = blockIdx.x;
    if (tid < NB) cur[tid] = base[(size_t)tid * G + blk];
    __syncthreads();
    int q0 = blk * (EPB / 4), q1 = q0 + (EPB / 4);
    const int qmax = NEDGES / 4;
    if (q1 > qmax) q1 = qmax;
    for (int q = q0 + tid; q < q1; q += 256) {
        int4   r4 = ((const int4*)rows)[q];
        int4   c4 = ((const int4*)cols)[q];
        float4 v4 = ((const float4*)vals)[q];
        int s0 = atomicAdd(&cur[r4.x >> BKT_SHIFT], 1);
        bedge[s0] = make_int2(c4.x | ((r4.x & 1023) << 18), __float_as_int(v4.x));
        int s1 = atomicAdd(&cur[r4.y >> BKT_SHIFT], 1);
        bedge[s1] = make_int2(c4.y | ((r4.y & 1023) << 18), __float_as_int(v4.y));
        int s2 = atomicAdd(&cur[r4.z >> BKT_SHIFT], 1);
        bedge[s2] = make_int2(c4.z | ((r4.z & 1023) << 18), __float_as_int(v4.z));
        int s3 = atomicAdd(&cur[r4.w >> BKT_SHIFT], 1);
        bedge[s3] = make_int2(c4.w | ((r4.w & 1023) << 18), __float_as_int(v4.w));
    }
}

// P3: per-bucket counting sort by (rowLocal, col>>14) -> CSR + rowptr
__global__ __launch_bounds__(1024) void bucket_csr(
        const int2* __restrict__ bedge, const int* __restrict__ base,
        int* __restrict__ rowptr, int2* __restrict__ csr) {
    __shared__ int h[NBINS];        // 40 KB: bin counts -> absolute cursors
    __shared__ int tsum[1024];
    int tid = threadIdx.x, bkt = blockIdx.x;
    int s  = base[(size_t)bkt * G];
    int e2 = base[(size_t)(bkt + 1) * G];     // bkt+1==NB -> base[NSCAN] = NEDGES
    for (int i = tid; i < NBINS; i += 1024) h[i] = 0;
    __syncthreads();
    for (int i = s + tid; i < e2; i += 1024) {
        int x = bedge[i].x;
        int bin = (x >> 18) * NSLICE + (((unsigned)x & 0x3FFFFu) >> SLICE_SHIFT);
        atomicAdd(&h[bin], 1);
    }
    __syncthreads();
    int b0 = tid * NSLICE;
    int cnt[NSLICE];
    int run = 0;
    #pragma unroll
    for (int i = 0; i < NSLICE; ++i) { cnt[i] = h[b0 + i]; run += cnt[i]; }
    tsum[tid] = run;
    __syncthreads();
    for (int off = 1; off < 1024; off <<= 1) {
        int t = (tid >= off) ? tsum[tid - off] : 0;
        __syncthreads();
        tsum[tid] += t;
        __syncthreads();
    }
    int excl = s + tsum[tid] - run;           // absolute start of row (bkt*1024+tid)
    int rbase = bkt << BKT_SHIFT;
    if (rbase + tid < NNODES) rowptr[rbase + tid] = excl;
    if (bkt == NB - 1 && tid == 0) rowptr[NNODES] = NEDGES;
    #pragma unroll
    for (int i = 0; i < NSLICE; ++i) { int c = cnt[i]; h[b0 + i] = excl; excl += c; }
    __syncthreads();
    for (int i = s + tid; i < e2; i += 1024) {
        int2 t = bedge[i];
        int bin = (t.x >> 18) * NSLICE + (((unsigned)t.x & 0x3FFFFu) >> SLICE_SHIFT);
        int slot = atomicAdd(&h[bin], 1);
        csr[slot] = make_int2(t.x & 0x3FFFF, t.y);
    }
}

// ---------------- degree-balance sort: rorder = rows sorted by degree ----------
__global__ __launch_bounds__(1024) void deg_hist(const int* __restrict__ rowptr,
                                                 int* __restrict__ ghist) {
    __shared__ int h[NDEG];
    int tid = threadIdx.x;
    int r = blockIdx.x * 1024 + tid;
    if (tid < NDEG) h[tid] = 0;
    __syncthreads();
    if (r < NNODES) {
        int d = rowptr[r + 1] - rowptr[r];
        if (d > NDEG - 1) d = NDEG - 1;
        atomicAdd(&h[d], 1);
    }
    __syncthreads();
    if (tid < NDEG && h[tid]) atomicAdd(&ghist[tid], h[tid]);
}

// exclusive scan of NDEG bins (single wave-free simple block scan)
__global__ void deg_scan(int* __restrict__ ghist) {
    __shared__ int buf[NDEG];
    int tid = threadIdx.x;      // 128 threads
    int v = ghist[tid];
    buf[tid] = v;
    __syncthreads();
    for (int off = 1; off < NDEG; off <<= 1) {
        int t = (tid >= off) ? buf[tid - off] : 0;
        __syncthreads();
        buf[tid] += t;
        __syncthreads();
    }
    ghist[tid] = buf[tid] - v;  // exclusive
}

__global__ __launch_bounds__(1024) void deg_scatter(const int* __restrict__ rowptr,
                                                    int* __restrict__ gcur,
                                                    int* __restrict__ rorder) {
    __shared__ int h[NDEG];
    __shared__ int basev[NDEG];
    __shared__ int c2[NDEG];
    int tid = threadIdx.x;
    int r = blockIdx.x * 1024 + tid;
    if (tid < NDEG) { h[tid] = 0; c2[tid] = 0; }
    __syncthreads();
    int d = -1;
    if (r < NNODES) {
        d = rowptr[r + 1] - rowptr[r];
        if (d > NDEG - 1) d = NDEG - 1;
        atomicAdd(&h[d], 1);
    }
    __syncthreads();
    if (tid < NDEG && h[tid]) basev[tid] = atomicAdd(&gcur[tid], h[tid]);
    __syncthreads();
    if (r < NNODES) {
        int rank = atomicAdd(&c2[d], 1);
        rorder[basev[d] + rank] = r;
    }
}

// ---------------- gather-only SpMM: sideb = bf16( A @ egoc ) ----------------
// one row per 8-lane group via degree-sorted rorder (uniform wave lifetimes).
#define ACC8(g, v)                                              \
    a0 = fmaf(v, __uint_as_float((g).x << 16), a0);             \
    a1 = fmaf(v, __uint_as_float((g).x & 0xffff0000u), a1);     \
    a2 = fmaf(v, __uint_as_float((g).y << 16), a2);             \
    a3 = fmaf(v, __uint_as_float((g).y & 0xffff0000u), a3);     \
    a4 = fmaf(v, __uint_as_float((g).z << 16), a4);             \
    a5 = fmaf(v, __uint_as_float((g).z & 0xffff0000u), a5);     \
    a6 = fmaf(v, __uint_as_float((g).w << 16), a6);             \
    a7 = fmaf(v, __uint_as_float((g).w & 0xffff0000u), a7);

__global__ __launch_bounds__(512) void spmm_gather(
        const int* __restrict__ rowptr, const int* __restrict__ rorder,
        const int2* __restrict__ csr,
        const unsigned short* __restrict__ egoc,   // bf16 [NNODES][64]
        unsigned short* __restrict__ sideb,        // bf16, row stride strideE ushorts
        int strideE) {
    int tid = blockIdx.x * blockDim.x + threadIdx.x;
    int rid = tid >> 3;
    int dg  = tid & 7;
    if (rid >= NNODES) return;
    int row = rorder[rid];
    int s = rowptr[row], e = rowptr[row + 1];
    const uint4* egc = (const uint4*)egoc;
    float a0 = 0.f, a1 = 0.f, a2 = 0.f, a3 = 0.f,
          a4 = 0.f, a5 = 0.f, a6 = 0.f, a7 = 0.f;
    for (int b = s; b < e; b += 4) {
        int i1 = b + 1 < e ? b + 1 : e - 1;
        int i2 = b + 2 < e ? b + 2 : e - 1;
        int i3 = b + 3 < e ? b + 3 : e - 1;
        int2 cv0 = csr[b], cv1 = csr[i1], cv2 = csr[i2], cv3 = csr[i3];
        float v0 = __int_as_float(cv0.y);
        float v1 = (b + 1 < e) ? __int_as_float(cv1.y) : 0.f;
        float v2 = (b + 2 < e) ? __int_as_float(cv2.y) : 0.f;
        float v3 = (b + 3 < e) ? __int_as_float(cv3.y) : 0.f;
        uint4 g0 = egc[(size_t)cv0.x * 8 + dg];
        uint4 g1 = egc[(size_t)cv1.x * 8 + dg];
        uint4 g2 = egc[(size_t)cv2.x * 8 + dg];
        uint4 g3 = egc[(size_t)cv3.x * 8 + dg];
        ACC8(g0, v0); ACC8(g1, v1); ACC8(g2, v2); ACC8(g3, v3);
    }
    uint p0 = (unsigned)f2bf(a0) | ((unsigned)f2bf(a1) << 16);
    uint p1 = (unsigned)f2bf(a2) | ((unsigned)f2bf(a3) << 16);
    uint p2 = (unsigned)f2bf(a4) | ((unsigned)f2bf(a5) << 16);
    uint p3 = (unsigned)f2bf(a6) | ((unsigned)f2bf(a7) << 16);
    uint4 st = make_uint4(p0, p1, p2, p3);
    *(uint4*)(sideb + (size_t)row * strideE + dg * 8) = st;
}

// ---------------- dense layer via MFMA ----------------
__global__ __launch_bounds__(256) void dense_mfma(
        const unsigned short* __restrict__ sideb, int sStrideE,
        const unsigned short* __restrict__ egoc,   // bf16 [NNODES][64]
        const unsigned short* __restrict__ wg,     // bf16 [64][64] (row c, col k)
        const unsigned short* __restrict__ wb,
        const float* __restrict__ bg, const float* __restrict__ bb,
        float* __restrict__ outCol,                // f32, stride OUTC
        unsigned short* __restrict__ egocNew) {    // bf16 [NNODES][64] or null
    int lane = threadIdx.x & 63;
    int ct   = (threadIdx.x >> 6) * 16;       // col tile (wave id * 16)
    int rtile = blockIdx.x * 16;
    int ar = lane & 15, kg = lane >> 4;
    bf16x8 sfrag[2], pfrag[2], wgf[2], wbf[2];
    #pragma unroll
    for (int t = 0; t < 2; ++t) {
        int koff = kg * 8 + 32 * t;            // bf16 element offset in k
        bf16x8 sv = *(const bf16x8*)(sideb + (size_t)(rtile + ar) * sStrideE + koff);
        bf16x8 ev = *(const bf16x8*)(egoc  + (size_t)(rtile + ar) * EMB + koff);
        sfrag[t] = sv;
        bf16x8 pv;
        #pragma unroll
        for (int j = 0; j < 8; ++j)
            pv[j] = (short)f2bf(bf2f(sv[j]) * bf2f(ev[j]));
        pfrag[t] = pv;
        wgf[t] = *(const bf16x8*)(wg + (size_t)(ct + ar) * EMB + koff);
        wbf[t] = *(const bf16x8*)(wb + (size_t)(ct + ar) * EMB + koff);
    }
    f32x4 accg = {0.f, 0.f, 0.f, 0.f}, accb = {0.f, 0.f, 0.f, 0.f};
    accg = __builtin_amdgcn_mfma_f32_16x16x32_bf16(sfrag[0], wgf[0], accg, 0, 0, 0);
    accg = __builtin_amdgcn_mfma_f32_16x16x32_bf16(sfrag[1], wgf[1], accg, 0, 0, 0);
    accb = __builtin_amdgcn_mfma_f32_16x16x32_bf16(pfrag[0], wbf[0], accb, 0, 0, 0);
    accb = __builtin_amdgcn_mfma_f32_16x16x32_bf16(pfrag[1], wbf[1], accb, 0, 0, 0);
    int c = ct + ar;                            // C/D: col = lane&15
    float biasg = bg[c], biasb = bb[c];
    #pragma unroll
    for (int i = 0; i < 4; ++i) {
        int r = rtile + kg * 4 + i;             // C/D: row = (lane>>4)*4 + reg
        float g = accg[i] + biasg; g = (g > 0.f) ? g : NEG_SLOPE * g;
        float q = accb[i] + biasb; q = (q > 0.f) ? q : NEG_SLOPE * q;
        float nv = g + q;
        outCol[(size_t)r * OUTC + c] = nv;
        if (egocNew) egocNew[(size_t)r * EMB + c] = f2bf(nv);
    }
}

extern "C" void kernel_launch(void* const* d_in, const int* in_sizes, int n_in,
                              void* d_out, int out_size, void* d_ws, size_t ws_size,
                              hipStream_t stream) {
    const int*   ui   = (const int*)  d_in[0];
    const int*   ii   = (const int*)  d_in[1];
    const int*   rows = (const int*)  d_in[2];
    const int*   cols = (const int*)  d_in[3];
    const float* vals = (const float*)d_in[4];
    const float* uemb = (const float*)d_in[5];
    const float* iemb = (const float*)d_in[6];
    const float* Wg0 = (const float*)d_in[7],  *bg0 = (const float*)d_in[8];
    const float* Wb0 = (const float*)d_in[9],  *bb0 = (const float*)d_in[10];
    const float* Wg1 = (const float*)d_in[11], *bg1 = (const float*)d_in[12];
    const float* Wb1 = (const float*)d_in[13], *bb1 = (const float*)d_in[14];
    float* out = (float*)d_out;

    char* ws = (char*)d_ws;
    int2*  csr    = (int2*)ws; ws += (size_t)NEDGES * 8;                 // 38.4 MB
    char*  buf0   = ws;        ws += (size_t)NNODES * EMB * 2;           // 19.2 MB: bedge lo -> side1
    char*  buf1   = ws;        ws += (size_t)NNODES * EMB * 2;           // 19.2 MB: bedge hi -> egoc1
    unsigned short* egoc0 = (unsigned short*)ws; ws += (size_t)NNODES * EMB * 2; // 19.2 MB
    int*   rowptr = (int*) ws; ws += (size_t)(NNODES + 1) * 4;
    int*   hist   = (int*) ws; ws += (size_t)NSCAN * 4;                  // 0.60 MB
    int*   scanb  = (int*) ws; ws += (size_t)(NSCAN + 1) * 4;            // 0.60 MB
    int*   blksum = (int*) ws; ws += 256 * 4;
    int*   rorder = (int*) ws; ws += (size_t)NNODES * 4;                 // 0.60 MB
    int*   ghist  = (int*) ws; ws += NDEG * 4;
    unsigned short* wgb0 = (unsigned short*)ws; ws += 4096 * 2;
    unsigned short* wbb0 = (unsigned short*)ws; ws += 4096 * 2;
    unsigned short* wgb1 = (unsigned short*)ws; ws += 4096 * 2;
    unsigned short* wbb1 = (unsigned short*)ws; ws += 4096 * 2;
    int2* bedge = (int2*)buf0;                     // 38.4 MB spans buf0+buf1
    unsigned short* egoc1 = (unsigned short*)buf1;

    const int RBLK = (NNODES + 1023) / 1024;   // 147

    // ego0 -> out cols [0,64) AND bf16 egoc0 (fused); bf16 weights (one kernel)
    build_ego<<<(NNODES * 16 + 255) / 256, 256, 0, stream>>>(ui, ii, uemb, iemb,
                                                             out, egoc0);
    conv_w4<<<16, 256, 0, stream>>>(Wg0, Wb0, Wg1, Wb1, wgb0, wbb0, wgb1, wbb1);

    // CSR build: bucket partition (LDS atomics only), col-sorted within rows
    bucket_hist<<<G, 256, 0, stream>>>(rows, hist);
    scan_chunk<<<NSCAN / 1024, 1024, 0, stream>>>(hist, scanb, blksum, NSCAN);
    scan_sums<<<1, 256, 0, stream>>>(blksum, NSCAN / 1024);
    add_offsets<<<NSCAN / 1024, 1024, 0, stream>>>(scanb, blksum, NSCAN);
    bucket_scatter<<<G, 256, 0, stream>>>(rows, cols, vals, scanb, bedge);
    bucket_csr<<<NB, 1024, 0, stream>>>(bedge, scanb, rowptr, csr);

    // degree-balance row order
    hipMemsetAsync(ghist, 0, NDEG * 4, stream);
    deg_hist<<<RBLK, 1024, 0, stream>>>(rowptr, ghist);
    deg_scan<<<1, NDEG, 0, stream>>>(ghist);
    deg_scatter<<<RBLK, 1024, 0, stream>>>(rowptr, ghist, rorder);

    // L0 sideb: stash bf16 side in out cols [128,192) region (row stride 768B, offset 512B)
    unsigned short* side0 = (unsigned short*)((char*)out + 512);
    const int SIDE0_STRIDE = 384;   // ushorts (= 768B)
    spmm_gather<<<(NNODES * 8 + 511) / 512, 512, 0, stream>>>(rowptr, rorder, csr,
                                                              egoc0, side0, SIDE0_STRIDE);
    dense_mfma<<<NNODES / 16, 256, 0, stream>>>(side0, SIDE0_STRIDE, egoc0,
                                                wgb0, wbb0, bg0, bb0,
                                                out + 64, egoc1);          // bedge dead now

    // L1 sideb: buf0 (bedge-lo dead after L0 spmm)
    unsigned short* side1 = (unsigned short*)buf0;
    spmm_gather<<<(NNODES * 8 + 511) / 512, 512, 0, stream>>>(rowptr, rorder, csr,
                                                              egoc1, side1, EMB);
    dense_mfma<<<NNODES / 16, 256, 0, stream>>>(side1, EMB, egoc1,
                                                wgb1, wbb1, bg1, bb1,
                                                out + 128, (unsigned short*)nullptr);
}

// Round 11
// 399.643 us; speedup vs baseline: 1.0695x; 1.0695x over previous
//
#include <hip/hip_runtime.h>

#define NUSERS 100000
#define NITEMS 50000
#define NNODES 150000   // NUSERS + NITEMS
#define EMB 64
#define NEDGES 4800000
#define OUTC 192        // 3 * EMB concatenated output columns
#define NEG_SLOPE 0.01f

#define BKT_SHIFT 10
#define NB 147          // ceil(NNODES / 1024)
#define G 1024          // blocks in hist/scatter passes
#define EPB 4688        // ceil(NEDGES / G), multiple of 4
#define NSCAN (NB * G)  // 150528

typedef __attribute__((ext_vector_type(8))) short bf16x8;
typedef __attribute__((ext_vector_type(4))) float f32x4;

__device__ __forceinline__ unsigned short f2bf(float f) {
    unsigned u = __float_as_uint(f);
    unsigned r = (u + 0x7fffu + ((u >> 16) & 1u)) >> 16;   // RN-even
    return (unsigned short)r;
}
__device__ __forceinline__ float bf2f(short s) {
    return __uint_as_float(((unsigned)(unsigned short)s) << 16);
}

// ---------------- ego0 build: gather embeddings -> out cols 0:64 AND bf16 egoc0
__global__ void build_ego(const int* __restrict__ ui, const int* __restrict__ ii,
                          const float* __restrict__ uemb, const float* __restrict__ iemb,
                          float* __restrict__ out, unsigned short* __restrict__ egoc) {
    int gid = blockIdx.x * blockDim.x + threadIdx.x;   // one float4 per thread
    int r = gid >> 4, p = gid & 15;
    if (r >= NNODES) return;
    const float* src = (r < NUSERS) ? (uemb + (size_t)ui[r] * EMB)
                                    : (iemb + (size_t)ii[r - NUSERS] * EMB);
    float4 v = ((const float4*)src)[p];
    *(float4*)(out + (size_t)r * OUTC + p * 4) = v;
    ushort4 o;
    o.x = f2bf(v.x); o.y = f2bf(v.y); o.z = f2bf(v.z); o.w = f2bf(v.w);
    *(ushort4*)(egoc + (size_t)r * EMB + p * 4) = o;
}

// all 4 weight matrices f32 [64][64] -> bf16 in one kernel
__global__ void conv_w4(const float* __restrict__ s0, const float* __restrict__ s1,
                        const float* __restrict__ s2, const float* __restrict__ s3,
                        unsigned short* __restrict__ d0, unsigned short* __restrict__ d1,
                        unsigned short* __restrict__ d2, unsigned short* __restrict__ d3) {
    int i = blockIdx.x * 256 + threadIdx.x;
    if (i < 4096) {
        d0[i] = f2bf(s0[i]); d1[i] = f2bf(s1[i]);
        d2[i] = f2bf(s2[i]); d3[i] = f2bf(s3[i]);
    }
}

// ---------------- CSR build: bucket partition, LDS atomics only ----------------
// P1: per-block 147-bucket LDS histogram (int4 edge reads)
__global__ __launch_bounds__(256) void bucket_hist(const int* __restrict__ rows,
                                                   int* __restrict__ hist) {
    __shared__ int h[NB];
    int tid = threadIdx.x, blk = blockIdx.x;
    if (tid < NB) h[tid] = 0;
    __syncthreads();
    int q0 = blk * (EPB / 4), q1 = q0 + (EPB / 4);
    const int qmax = NEDGES / 4;
    if (q1 > qmax) q1 = qmax;
    for (int q = q0 + tid; q < q1; q += 256) {
        int4 r4 = ((const int4*)rows)[q];
        atomicAdd(&h[r4.x >> BKT_SHIFT], 1);
        atomicAdd(&h[r4.y >> BKT_SHIFT], 1);
        atomicAdd(&h[r4.z >> BKT_SHIFT], 1);
        atomicAdd(&h[r4.w >> BKT_SHIFT], 1);
    }
    __syncthreads();
    if (tid < NB) hist[(size_t)tid * G + blk] = h[tid];   // bucket-major
}

// inclusive scan of 1024-chunks -> outp[i+1]; block totals to blksum
__global__ void scan_chunk(const int* __restrict__ counts, int* __restrict__ outp,
                           int* __restrict__ blksum, int n) {
    __shared__ int buf[1024];
    int tid = threadIdx.x;
    int gid = blockIdx.x * 1024 + tid;
    int v = (gid < n) ? counts[gid] : 0;
    buf[tid] = v;
    __syncthreads();
    for (int off = 1; off < 1024; off <<= 1) {
        int t = (tid >= off) ? buf[tid - off] : 0;
        __syncthreads();
        buf[tid] += t;
        __syncthreads();
    }
    if (gid < n) outp[gid + 1] = buf[tid];
    if (tid == 1023) blksum[blockIdx.x] = buf[tid];
}

__global__ void scan_sums(int* __restrict__ blksum, int n) {
    __shared__ int buf[256];
    int tid = threadIdx.x;
    int v = (tid < n) ? blksum[tid] : 0;
    buf[tid] = v;
    __syncthreads();
    for (int off = 1; off < 256; off <<= 1) {
        int t = (tid >= off) ? buf[tid - off] : 0;
        __syncthreads();
        buf[tid] += t;
        __syncthreads();
    }
    if (tid < n) blksum[tid] = buf[tid] - v;  // exclusive
}

__global__ void add_offsets(int* __restrict__ outp, const int* __restrict__ blksum, int n) {
    int gid = blockIdx.x * 1024 + threadIdx.x;
    if (gid < n) outp[gid + 1] += blksum[blockIdx.x];
    if (gid == 0) outp[0] = 0;
}

// P2: scatter edges into bucket-partitioned array (int4 reads, LDS cursors)
__global__ __launch_bounds__(256) void bucket_scatter(
        const int* __restrict__ rows, const int* __restrict__ cols,
        const float* __restrict__ vals, const int* __restrict__ base,
        int2* __restrict__ bedge) {
    __shared__ int cur[NB];
    int tid = threadIdx.x, blk = blockIdx.x;
    if (tid < NB) cur[tid] = base[(size_t)tid * G + blk];
    __syncthreads();
    int q0 = blk * (EPB / 4), q1 = q0 + (EPB / 4);
    const int qmax = NEDGES / 4;
    if (q1 > qmax) q1 = qmax;
    for (int q = q0 + tid; q < q1; q += 256) {
        int4   r4 = ((const int4*)rows)[q];
        int4   c4 = ((const int4*)cols)[q];
        float4 v4 = ((const float4*)vals)[q];
        int s0 = atomicAdd(&cur[r4.x >> BKT_SHIFT], 1);
        bedge[s0] = make_int2(c4.x | ((r4.x & 1023) << 18), __float_as_int(v4.x));
        int s1 = atomicAdd(&cur[r4.y >> BKT_SHIFT], 1);
        bedge[s1] = make_int2(c4.y | ((r4.y & 1023) << 18), __float_as_int(v4.y));
        int s2 = atomicAdd(&cur[r4.z >> BKT_SHIFT], 1);
        bedge[s2] = make_int2(c4.z | ((r4.z & 1023) << 18), __float_as_int(v4.z));
        int s3 = atomicAdd(&cur[r4.w >> BKT_SHIFT], 1);
        bedge[s3] = make_int2(c4.w | ((r4.w & 1023) << 18), __float_as_int(v4.w));
    }
}

// P3: per-bucket (1024 rows) LDS histogram + in-block scan -> rowptr; then
// LDS-cursor scatter into final CSR (bucket window ~262KB, L2-resident).
__global__ __launch_bounds__(1024) void bucket_csr(
        const int2* __restrict__ bedge, const int* __restrict__ base,
        int* __restrict__ rowptr, int2* __restrict__ csr) {
    __shared__ int h[1024];
    __shared__ int h2[1024];
    int tid = threadIdx.x, bkt = blockIdx.x;
    int s  = base[(size_t)bkt * G];
    int e2 = base[(size_t)(bkt + 1) * G];     // bkt+1==NB -> base[NSCAN] = NEDGES
    h[tid] = 0;
    __syncthreads();
    for (int i = s + tid; i < e2; i += 1024)
        atomicAdd(&h[(unsigned)bedge[i].x >> 18], 1);
    __syncthreads();
    int v = h[tid];
    h2[tid] = v;
    __syncthreads();
    for (int off = 1; off < 1024; off <<= 1) {
        int t = (tid >= off) ? h2[tid - off] : 0;
        __syncthreads();
        h2[tid] += t;
        __syncthreads();
    }
    int excl = s + h2[tid] - v;               // absolute row start
    int rbase = bkt << BKT_SHIFT;
    if (rbase + tid < NNODES) rowptr[rbase + tid] = excl;
    if (bkt == NB - 1 && tid == 0) rowptr[NNODES] = NEDGES;
    h[tid] = excl;                            // reuse as cursor
    __syncthreads();
    for (int i = s + tid; i < e2; i += 1024) {
        int2 t = bedge[i];
        int slot = atomicAdd(&h[(unsigned)t.x >> 18], 1);
        csr[slot] = make_int2(t.x & 0x3FFFF, t.y);
    }
}

// ---------------- gather-only SpMM: sideb = bf16( A @ egoc ) ----------------
// one row per 8-lane group; lane owns dims [8dg, 8dg+8). No cross-lane ops.
// 4 edges unrolled -> 4 independent uint4 gathers in flight per lane.
#define ACC8(g, v)                                              \
    a0 = fmaf(v, __uint_as_float((g).x << 16), a0);             \
    a1 = fmaf(v, __uint_as_float((g).x & 0xffff0000u), a1);     \
    a2 = fmaf(v, __uint_as_float((g).y << 16), a2);             \
    a3 = fmaf(v, __uint_as_float((g).y & 0xffff0000u), a3);     \
    a4 = fmaf(v, __uint_as_float((g).z << 16), a4);             \
    a5 = fmaf(v, __uint_as_float((g).z & 0xffff0000u), a5);     \
    a6 = fmaf(v, __uint_as_float((g).w << 16), a6);             \
    a7 = fmaf(v, __uint_as_float((g).w & 0xffff0000u), a7);

__global__ __launch_bounds__(512) void spmm_gather(
        const int* __restrict__ rowptr, const int2* __restrict__ csr,
        const unsigned short* __restrict__ egoc,   // bf16 [NNODES][64]
        unsigned short* __restrict__ sideb,        // bf16, row stride strideE ushorts
        int strideE) {
    int tid = blockIdx.x * blockDim.x + threadIdx.x;
    int row = tid >> 3;
    int dg  = tid & 7;
    if (row >= NNODES) return;
    int s = rowptr[row], e = rowptr[row + 1];
    const uint4* egc = (const uint4*)egoc;
    float a0 = 0.f, a1 = 0.f, a2 = 0.f, a3 = 0.f,
          a4 = 0.f, a5 = 0.f, a6 = 0.f, a7 = 0.f;
    for (int b = s; b < e; b += 4) {
        int i1 = b + 1 < e ? b + 1 : e - 1;
        int i2 = b + 2 < e ? b + 2 : e - 1;
        int i3 = b + 3 < e ? b + 3 : e - 1;
        int2 cv0 = csr[b], cv1 = csr[i1], cv2 = csr[i2], cv3 = csr[i3];
        float v0 = __int_as_float(cv0.y);
        float v1 = (b + 1 < e) ? __int_as_float(cv1.y) : 0.f;
        float v2 = (b + 2 < e) ? __int_as_float(cv2.y) : 0.f;
        float v3 = (b + 3 < e) ? __int_as_float(cv3.y) : 0.f;
        uint4 g0 = egc[(size_t)cv0.x * 8 + dg];
        uint4 g1 = egc[(size_t)cv1.x * 8 + dg];
        uint4 g2 = egc[(size_t)cv2.x * 8 + dg];
        uint4 g3 = egc[(size_t)cv3.x * 8 + dg];
        ACC8(g0, v0); ACC8(g1, v1); ACC8(g2, v2); ACC8(g3, v3);
    }
    uint p0 = (unsigned)f2bf(a0) | ((unsigned)f2bf(a1) << 16);
    uint p1 = (unsigned)f2bf(a2) | ((unsigned)f2bf(a3) << 16);
    uint p2 = (unsigned)f2bf(a4) | ((unsigned)f2bf(a5) << 16);
    uint p3 = (unsigned)f2bf(a6) | ((unsigned)f2bf(a7) << 16);
    uint4 st = make_uint4(p0, p1, p2, p3);
    *(uint4*)(sideb + (size_t)row * strideE + dg * 8) = st;
}

// ---------------- dense layer via MFMA ----------------
__global__ __launch_bounds__(256) void dense_mfma(
        const unsigned short* __restrict__ sideb, int sStrideE,
        const unsigned short* __restrict__ egoc,   // bf16 [NNODES][64]
        const unsigned short* __restrict__ wg,     // bf16 [64][64] (row c, col k)
        const unsigned short* __restrict__ wb,
        const float* __restrict__ bg, const float* __restrict__ bb,
        float* __restrict__ outCol,                // f32, stride OUTC
        unsigned short* __restrict__ egocNew) {    // bf16 [NNODES][64] or null
    int lane = threadIdx.x & 63;
    int ct   = (threadIdx.x >> 6) * 16;       // col tile (wave id * 16)
    int rtile = blockIdx.x * 16;
    int ar = lane & 15, kg = lane >> 4;
    bf16x8 sfrag[2], pfrag[2], wgf[2], wbf[2];
    #pragma unroll
    for (int t = 0; t < 2; ++t) {
        int koff = kg * 8 + 32 * t;            // bf16 element offset in k
        bf16x8 sv = *(const bf16x8*)(sideb + (size_t)(rtile + ar) * sStrideE + koff);
        bf16x8 ev = *(const bf16x8*)(egoc  + (size_t)(rtile + ar) * EMB + koff);
        sfrag[t] = sv;
        bf16x8 pv;
        #pragma unroll
        for (int j = 0; j < 8; ++j)
            pv[j] = (short)f2bf(bf2f(sv[j]) * bf2f(ev[j]));
        pfrag[t] = pv;
        wgf[t] = *(const bf16x8*)(wg + (size_t)(ct + ar) * EMB + koff);
        wbf[t] = *(const bf16x8*)(wb + (size_t)(ct + ar) * EMB + koff);
    }
    f32x4 accg = {0.f, 0.f, 0.f, 0.f}, accb = {0.f, 0.f, 0.f, 0.f};
    accg = __builtin_amdgcn_mfma_f32_16x16x32_bf16(sfrag[0], wgf[0], accg, 0, 0, 0);
    accg = __builtin_amdgcn_mfma_f32_16x16x32_bf16(sfrag[1], wgf[1], accg, 0, 0, 0);
    accb = __builtin_amdgcn_mfma_f32_16x16x32_bf16(pfrag[0], wbf[0], accb, 0, 0, 0);
    accb = __builtin_amdgcn_mfma_f32_16x16x32_bf16(pfrag[1], wbf[1], accb, 0, 0, 0);
    int c = ct + ar;                            // C/D: col = lane&15
    float biasg = bg[c], biasb = bb[c];
    #pragma unroll
    for (int i = 0; i < 4; ++i) {
        int r = rtile + kg * 4 + i;             // C/D: row = (lane>>4)*4 + reg
        float g = accg[i] + biasg; g = (g > 0.f) ? g : NEG_SLOPE * g;
        float q = accb[i] + biasb; q = (q > 0.f) ? q : NEG_SLOPE * q;
        float nv = g + q;
        outCol[(size_t)r * OUTC + c] = nv;
        if (egocNew) egocNew[(size_t)r * EMB + c] = f2bf(nv);
    }
}

extern "C" void kernel_launch(void* const* d_in, const int* in_sizes, int n_in,
                              void* d_out, int out_size, void* d_ws, size_t ws_size,
                              hipStream_t stream) {
    const int*   ui   = (const int*)  d_in[0];
    const int*   ii   = (const int*)  d_in[1];
    const int*   rows = (const int*)  d_in[2];
    const int*   cols = (const int*)  d_in[3];
    const float* vals = (const float*)d_in[4];
    const float* uemb = (const float*)d_in[5];
    const float* iemb = (const float*)d_in[6];
    const float* Wg0 = (const float*)d_in[7],  *bg0 = (const float*)d_in[8];
    const float* Wb0 = (const float*)d_in[9],  *bb0 = (const float*)d_in[10];
    const float* Wg1 = (const float*)d_in[11], *bg1 = (const float*)d_in[12];
    const float* Wb1 = (const float*)d_in[13], *bb1 = (const float*)d_in[14];
    float* out = (float*)d_out;

    char* ws = (char*)d_ws;
    int2*  csr    = (int2*)ws; ws += (size_t)NEDGES * 8;                 // 38.4 MB
    char*  buf0   = ws;        ws += (size_t)NNODES * EMB * 2;           // 19.2 MB: bedge lo -> side1
    char*  buf1   = ws;        ws += (size_t)NNODES * EMB * 2;           // 19.2 MB: bedge hi -> egoc1
    unsigned short* egoc0 = (unsigned short*)ws; ws += (size_t)NNODES * EMB * 2; // 19.2 MB
    int*   rowptr = (int*) ws; ws += (size_t)(NNODES + 1) * 4;
    int*   hist   = (int*) ws; ws += (size_t)NSCAN * 4;                  // 0.60 MB
    int*   scanb  = (int*) ws; ws += (size_t)(NSCAN + 1) * 4;            // 0.60 MB
    int*   blksum = (int*) ws; ws += 256 * 4;
    unsigned short* wgb0 = (unsigned short*)ws; ws += 4096 * 2;
    unsigned short* wbb0 = (unsigned short*)ws; ws += 4096 * 2;
    unsigned short* wgb1 = (unsigned short*)ws; ws += 4096 * 2;
    unsigned short* wbb1 = (unsigned short*)ws; ws += 4096 * 2;
    int2* bedge = (int2*)buf0;                     // 38.4 MB spans buf0+buf1
    unsigned short* egoc1 = (unsigned short*)buf1;

    // ego0 -> out cols [0,64) AND bf16 egoc0 (fused); bf16 weights (one kernel)
    build_ego<<<(NNODES * 16 + 255) / 256, 256, 0, stream>>>(ui, ii, uemb, iemb,
                                                             out, egoc0);
    conv_w4<<<16, 256, 0, stream>>>(Wg0, Wb0, Wg1, Wb1, wgb0, wbb0, wgb1, wbb1);

    // CSR build: bucket partition (LDS atomics only)
    bucket_hist<<<G, 256, 0, stream>>>(rows, hist);
    scan_chunk<<<NSCAN / 1024, 1024, 0, stream>>>(hist, scanb, blksum, NSCAN);
    scan_sums<<<1, 256, 0, stream>>>(blksum, NSCAN / 1024);
    add_offsets<<<NSCAN / 1024, 1024, 0, stream>>>(scanb, blksum, NSCAN);
    bucket_scatter<<<G, 256, 0, stream>>>(rows, cols, vals, scanb, bedge);
    bucket_csr<<<NB, 1024, 0, stream>>>(bedge, scanb, rowptr, csr);

    // L0 sideb: stash bf16 side in out cols [128,192) region (row stride 768B, offset 512B)
    unsigned short* side0 = (unsigned short*)((char*)out + 512);
    const int SIDE0_STRIDE = 384;   // ushorts (= 768B)
    spmm_gather<<<(NNODES * 8 + 511) / 512, 512, 0, stream>>>(rowptr, csr, egoc0,
                                                              side0, SIDE0_STRIDE);
    dense_mfma<<<NNODES / 16, 256, 0, stream>>>(side0, SIDE0_STRIDE, egoc0,
                                                wgb0, wbb0, bg0, bb0,
                                                out + 64, egoc1);          // bedge dead now

    // L1 sideb: buf0 (bedge-lo dead after L0 spmm)
    unsigned short* side1 = (unsigned short*)buf0;
    spmm_gather<<<(NNODES * 8 + 511) / 512, 512, 0, stream>>>(rowptr, csr, egoc1,
                                                              side1, EMB);
    dense_mfma<<<NNODES / 16, 256, 0, stream>>>(side1, EMB, egoc1,
                                                wgb1, wbb1, bg1, bb1,
                                                out + 128, (unsigned short*)nullptr);
}